// Round 10
// baseline (185.774 us; speedup 1.0000x reference)
//
#include <hip/hip_runtime.h>

typedef unsigned short u16t;
typedef __attribute__((ext_vector_type(8))) short bf16x8;
typedef __attribute__((ext_vector_type(4))) float f32x4;

#define DM   1024
#define SEQL 2048
#define NHD  16
#define HDD  64

#define GLL16(g, l) __builtin_amdgcn_global_load_lds( \
    (const __attribute__((address_space(1))) void*)(g), \
    (__attribute__((address_space(3))) void*)(l), 16, 0, 0)

#if defined(__has_builtin)
#if __has_builtin(__builtin_amdgcn_exp2f)
#define EXP2(x) __builtin_amdgcn_exp2f(x)
#else
#define EXP2(x) exp2f(x)
#endif
#else
#define EXP2(x) exp2f(x)
#endif

__device__ __forceinline__ u16t f2bf(float f) {
  unsigned u = __float_as_uint(f);
  return (u16t)((u + 0x7fffu + ((u >> 16) & 1u)) >> 16);   // RNE
}
// pack two finite floats to (bf16(a) | bf16(b)<<16), round-half-up
// (PROVEN numerics: 7.3e-4 absmax; v_cvt_pk_bf16_f32 regressed to 9e-3 — its
// rounding does not match, do not substitute)
__device__ __forceinline__ unsigned pack_bf16_2(float a, float b) {
  const unsigned ua = __float_as_uint(a) + 0x8000u;
  const unsigned ub = __float_as_uint(b) + 0x8000u;
  return __builtin_amdgcn_perm(ub, ua, 0x07060302);
}

// ---------------------------------------------------------------------------
// fp32 -> bf16 conversion: x (4M elems) + 4 weights (1M each)
// ---------------------------------------------------------------------------
struct ConvArgs { const float* src[5]; u16t* dst[5]; };

__global__ __launch_bounds__(256) void conv_kernel(ConvArgs a) {
  const int gid = blockIdx.x * 256 + threadIdx.x;
  const int e = gid << 2;
  int sel, off;
  if (e < 4194304) { sel = 0; off = e; }
  else { const int r = e - 4194304; sel = 1 + (r >> 20); off = r & 1048575; }
  const float4 f = *(const float4*)(a.src[sel] + off);
  union { u16t s[4]; uint2 u; } o;
  o.s[0] = f2bf(f.x); o.s[1] = f2bf(f.y); o.s[2] = f2bf(f.z); o.s[3] = f2bf(f.w);
  *(uint2*)(a.dst[sel] + off) = o.u;
}

__device__ __forceinline__ int gslot(int m, int kc) { return (m << 2) + (kc ^ ((m >> 1) & 3)); }

// ---------------------------------------------------------------------------
// FUSED Q+K GEMM block (r10). z=0 and z=1 blocks read IDENTICAL X tiles;
// fusing them stages X ONCE + Wq + Wk (24 KB/buf, 48 KB dbuf): barrier-drain
// per unit work halves on the QK portion (the only lever class that has won:
// constant/reduced staged bytes), X staging -17% of qkv total, and 12
// fragment reads feed 32 MFMAs vs 8/16 (LDS-read-per-MFMA -25%).
// Grid (8,32,2): 512 blocks -> each CU gets one heavy QK + one light V block.
// Epilogue: proven MODE1 epilogue twice (Es reuse is barrier-guarded).
// ---------------------------------------------------------------------------
__device__ __forceinline__ void qk_fused_body(
    const u16t* __restrict__ X, const u16t* __restrict__ Wq,
    const u16t* __restrict__ Wk, const float* __restrict__ bq,
    const float* __restrict__ bk, u16t* __restrict__ Qo,
    u16t* __restrict__ Ko, u16t* smem)
{
  u16t* const Es = smem;                 // 17408 elems, aliases staging

  const int tid = threadIdx.x;
  const int l = tid & 63, w = tid >> 6, q = l >> 4, ln = l & 15;
  const int trow0 = blockIdx.y << 7;    // token tile base
  const int dcol0 = blockIdx.x << 7;    // d tile base
  const int wm = (w >> 1) << 6, wn = (w & 1) << 6;

  const int s0 = tid, s1 = tid + 256;
  const int m0 = s0 >> 2, kc0 = (s0 & 3) ^ ((m0 >> 1) & 3);
  const int m1 = s1 >> 2, kc1 = (s1 & 3) ^ ((m1 >> 1) & 3);
  const u16t* gX0 = X  + (size_t)(trow0 + m0) * DM + (kc0 << 3);
  const u16t* gX1 = X  + (size_t)(trow0 + m1) * DM + (kc1 << 3);
  const u16t* gQ0 = Wq + (size_t)(dcol0 + m0) * DM + (kc0 << 3);
  const u16t* gQ1 = Wq + (size_t)(dcol0 + m1) * DM + (kc1 << 3);
  const u16t* gK0 = Wk + (size_t)(dcol0 + m0) * DM + (kc0 << 3);
  const u16t* gK1 = Wk + (size_t)(dcol0 + m1) * DM + (kc1 << 3);
  const int dO0 = (w << 6) << 3;               // wave-uniform LDS bases
  const int dO1 = ((w << 6) + 256) << 3;

  f32x4 accQ[4][4] = {};
  f32x4 accK[4][4] = {};

  // buffer layout (elems): X@0, Wq@4096, Wk@8192; buffers at 0 / 12288
  GLL16(gX0, smem + dO0);
  GLL16(gX1, smem + dO1);
  GLL16(gQ0, smem + 4096 + dO0);
  GLL16(gQ1, smem + 4096 + dO1);
  GLL16(gK0, smem + 8192 + dO0);
  GLL16(gK1, smem + 8192 + dO1);

  for (int kt = 0; kt < DM; kt += 32) {
    const int it = kt >> 5;
    u16t* const curX  = smem + ((it & 1) ? 12288 : 0);
    u16t* const curWq = curX + 4096;
    u16t* const curWk = curX + 8192;
    __syncthreads();                   // tile `it` loads complete; prev reads done
    if (kt + 32 < DM) {
      u16t* const nX = smem + ((it & 1) ? 0 : 12288);
      GLL16(gX0 + kt + 32, nX + dO0);
      GLL16(gX1 + kt + 32, nX + dO1);
      GLL16(gQ0 + kt + 32, nX + 4096 + dO0);
      GLL16(gQ1 + kt + 32, nX + 4096 + dO1);
      GLL16(gK0 + kt + 32, nX + 8192 + dO0);
      GLL16(gK1 + kt + 32, nX + 8192 + dO1);
    }

    bf16x8 bfr[4];
    #pragma unroll
    for (int ni = 0; ni < 4; ++ni)
      bfr[ni] = *(const bf16x8*)&curX[gslot(wn + (ni << 4) + ln, q) << 3];

    bf16x8 afQ[4], afK[4];
    #pragma unroll
    for (int mi = 0; mi < 4; ++mi) {
      const int r = wm + (mi << 4) + ln;
      afQ[mi] = *(const bf16x8*)&curWq[gslot(r, q) << 3];
      afK[mi] = *(const bf16x8*)&curWk[gslot(r, q) << 3];
    }
    #pragma unroll
    for (int mi = 0; mi < 4; ++mi)
      #pragma unroll
      for (int ni = 0; ni < 4; ++ni)
        accQ[mi][ni] = __builtin_amdgcn_mfma_f32_16x16x32_bf16(afQ[mi], bfr[ni], accQ[mi][ni], 0, 0, 0);
    #pragma unroll
    for (int mi = 0; mi < 4; ++mi)
      #pragma unroll
      for (int ni = 0; ni < 4; ++ni)
        accK[mi][ni] = __builtin_amdgcn_mfma_f32_16x16x32_bf16(afK[mi], bfr[ni], accK[mi][ni], 0, 0, 0);
  }

  // ---- epilogue x2 (Q then K), Es reuse barrier-guarded ----
  #pragma unroll
  for (int which = 0; which < 2; ++which) {
    const float oscale = which ? 1.0f : 0.04508422f;  // Q carries log2(e)/32
    const float* const bias = which ? bk : bq;
    u16t* const outB = which ? Ko : Qo;
    __syncthreads();   // staging dead (which=0) / prev Es reads done (which=1)
    #pragma unroll
    for (int mi = 0; mi < 4; ++mi) {
      const int dl = wm + (mi << 4) + (q << 2);
      const float4 b4 = *(const float4*)&bias[dcol0 + dl];
      #pragma unroll
      for (int ni = 0; ni < 4; ++ni) {
        const int tl = wn + (ni << 4) + ln;
        const f32x4 a = which ? accK[mi][ni] : accQ[mi][ni];
        uint2 pk;
        pk.x = pack_bf16_2((a[0] + b4.x) * oscale, (a[1] + b4.y) * oscale);
        pk.y = pack_bf16_2((a[2] + b4.z) * oscale, (a[3] + b4.w) * oscale);
        *(uint2*)&Es[tl * 136 + dl] = pk;
      }
    }
    __syncthreads();
    #pragma unroll
    for (int it = 0; it < 8; ++it) {
      const int u = (it << 8) + tid;
      const int tl = u >> 4, c8 = u & 15;
      const uint4 vv = *(const uint4*)&Es[tl * 136 + (c8 << 3)];
      const int tok = trow0 + tl;
      const int b = tok >> 11, n = tok & (SEQL - 1);
      const int dg = dcol0 + (c8 << 3);
      const int h = dg >> 6, hd = dg & 63;
      *(uint4*)&outB[((size_t)(b * NHD + h) * SEQL + n) * HDD + hd] = vv;
    }
  }
}

// ---------------------------------------------------------------------------
// V GEMM (MODE2 of the proven r4 qkv): 128x128 tile, BK=32, normal
// orientation, token groups permuted by gp, stored as V^T [bh][hd][n'].
// ---------------------------------------------------------------------------
__device__ __forceinline__ void v_body(
    const u16t* __restrict__ X, const u16t* __restrict__ W,
    const float* __restrict__ bias, u16t* __restrict__ outB,
    u16t* smem)
{
  u16t* const Es = smem;

  const int tid = threadIdx.x;
  const int l = tid & 63, w = tid >> 6, q = l >> 4, ln = l & 15;
  const int trow0 = blockIdx.y << 7;
  const int dcol0 = blockIdx.x << 7;
  const int wm = (w >> 1) << 6, wn = (w & 1) << 6;

  const int s0 = tid, s1 = tid + 256;
  const int m0 = s0 >> 2, kc0 = (s0 & 3) ^ ((m0 >> 1) & 3);
  const int m1 = s1 >> 2, kc1 = (s1 & 3) ^ ((m1 >> 1) & 3);
  const u16t* gA0 = X + (size_t)(trow0 + m0) * DM + (kc0 << 3);
  const u16t* gA1 = X + (size_t)(trow0 + m1) * DM + (kc1 << 3);
  const u16t* gB0 = W + (size_t)(dcol0 + m0) * DM + (kc0 << 3);
  const u16t* gB1 = W + (size_t)(dcol0 + m1) * DM + (kc1 << 3);
  const int dO0 = (w << 6) << 3;
  const int dO1 = ((w << 6) + 256) << 3;

  f32x4 acc[4][4] = {};

  GLL16(gA0, smem + dO0);
  GLL16(gA1, smem + dO1);
  GLL16(gB0, smem + 4096 + dO0);
  GLL16(gB1, smem + 4096 + dO1);

  for (int kt = 0; kt < DM; kt += 32) {
    const int it = kt >> 5;
    u16t* const curA = smem + ((it & 1) ? 8192 : 0);
    u16t* const curB = curA + 4096;
    __syncthreads();
    if (kt + 32 < DM) {
      u16t* const nA = smem + ((it & 1) ? 0 : 8192);
      u16t* const nB = nA + 4096;
      GLL16(gA0 + kt + 32, nA + dO0);
      GLL16(gA1 + kt + 32, nA + dO1);
      GLL16(gB0 + kt + 32, nB + dO0);
      GLL16(gB1 + kt + 32, nB + dO1);
    }

    bf16x8 af[4], bfr[4];
    #pragma unroll
    for (int mi = 0; mi < 4; ++mi)
      af[mi] = *(const bf16x8*)&curA[gslot(wm + (mi << 4) + ln, q) << 3];
    #pragma unroll
    for (int ni = 0; ni < 4; ++ni)
      bfr[ni] = *(const bf16x8*)&curB[gslot(wn + (ni << 4) + ln, q) << 3];
    #pragma unroll
    for (int mi = 0; mi < 4; ++mi)
      #pragma unroll
      for (int ni = 0; ni < 4; ++ni)
        acc[mi][ni] = __builtin_amdgcn_mfma_f32_16x16x32_bf16(af[mi], bfr[ni], acc[mi][ni], 0, 0, 0);
  }

  __syncthreads();
  #pragma unroll
  for (int ni = 0; ni < 4; ++ni) {
    const int dl = wn + (ni << 4) + ln;
    const float bv = bias[dcol0 + dl];
    #pragma unroll
    for (int mi = 0; mi < 4; ++mi) {
      const int g = (wm >> 2) + (mi << 2) + q;   // token group (of 4), 0..31
      const int g6 = g & 15;
      const int gp = (g & 16) | (g6 & 8) | ((g6 & 3) << 1) | ((g6 >> 2) & 1);
      uint2 pk;
      pk.x = pack_bf16_2(acc[mi][ni][0] + bv, acc[mi][ni][1] + bv);
      pk.y = pack_bf16_2(acc[mi][ni][2] + bv, acc[mi][ni][3] + bv);
      *(uint2*)&Es[dl * 136 + (gp << 2)] = pk;
    }
  }
  __syncthreads();
  #pragma unroll
  for (int it = 0; it < 8; ++it) {
    const int u = (it << 8) + tid;
    const int dl = u >> 4, c8 = u & 15;
    const uint4 vv = *(const uint4*)&Es[dl * 136 + (c8 << 3)];
    const int dg = dcol0 + dl;
    const int h = dg >> 6, hd = dg & 63;
    const int b = trow0 >> 11;
    const int n = (trow0 & (SEQL - 1)) + (c8 << 3);
    *(uint4*)&outB[((size_t)(b * NHD + h) * HDD + hd) * SEQL + n] = vv;
  }
}

struct QKVArgs { const u16t* W[3]; const float* b[3]; u16t* dst[3]; };

__global__ __launch_bounds__(256) void qkv_kernel(const u16t* __restrict__ X, QKVArgs g) {
  __shared__ alignas(16) u16t smem[24576];   // 48 KB (fused QK dbuf); Es aliases
  if (blockIdx.z == 0)
    qk_fused_body(X, g.W[0], g.W[1], g.b[0], g.b[1], g.dst[0], g.dst[1], smem);
  else
    v_body(X, g.W[2], g.b[2], g.dst[2], smem);
  // Q pre-scaled by log2(e)/32 so attention uses exp2 directly
}

// ---------------------------------------------------------------------------
// MFMA flash attention, SINGLE PASS over all 2048 keys. Q-TILE=128, KVBLK=64,
// double-buffered __syncthreads staging — the PROVEN r7 configuration.
// Geometry/pipeline axes exhausted: q-64 (+staging), KV-128 (22x conflicts),
// depth-2 vmcnt+sched_barrier (m141 failure mode, 43->52us). Parked.
// T5 setprio around MFMA clusters kept (r7: 46.1->43.3us, m191 regime).
// Block = (bh on x, q-tile on y) -> 512 blocks; linear id === bh (mod 8)
// pins each head's K/V to one XCD L2. Q direct global->regs. Row sums via
// ones-MFMA; P = exp2(S') since Q carries log2e/32. O normalized in-register.
// ---------------------------------------------------------------------------
__global__ __launch_bounds__(256, 4) void attn_kernel(
    const u16t* __restrict__ Qb, const u16t* __restrict__ Kb,
    const u16t* __restrict__ Vt, u16t* __restrict__ ctx)
{
  __shared__ alignas(16) u16t smem[16384];   // 32 KB: K/V dbuf; Os aliases

  const int tid = threadIdx.x;              // 0..255
  const int l = tid & 63, w = tid >> 6;     // wave 0..3
  const int q = l >> 4, ln = l & 15;
  const int bh = blockIdx.x, q0 = blockIdx.y << 7;
  const size_t hb = (size_t)bh * SEQL * HDD;
  const u16t* Qg = Qb + hb;
  const u16t* Kg = Kb + hb;
  const u16t* Vg = Vt + hb;   // [hd][n-permuted]

  bf16x8 qf[2][2];
  #pragma unroll
  for (int g = 0; g < 2; ++g) {
    const int qr = q0 + (w << 5) + (g << 4) + ln;
    #pragma unroll
    for (int ks = 0; ks < 2; ++ks)
      qf[g][ks] = *(const bf16x8*)(Qg + (size_t)qr * HDD + (((ks << 2) + q) << 3));
  }

  const int u0 = tid,       r0 = u0 >> 3, c0 = (u0 & 7) ^ (r0 & 7);
  const int u1 = 256 + tid, r1 = u1 >> 3, c1 = (u1 & 7) ^ (r1 & 7);
  const u16t* const kS0 = Kg + (size_t)r0 * HDD + (c0 << 3);
  const u16t* const kS1 = Kg + (size_t)r1 * HDD + (c1 << 3);
  const u16t* const vS0 = Vg + (size_t)r0 * SEQL + (c0 << 3);
  const u16t* const vS1 = Vg + (size_t)r1 * SEQL + (c1 << 3);
  const int dK0 = (w << 6) << 3, dK1 = (256 + (w << 6)) << 3;

  GLL16(kS0, smem + dK0);
  GLL16(kS1, smem + dK1);
  GLL16(vS0, smem + 4096 + dK0);
  GLL16(vS1, smem + 4096 + dK1);

  const short one_s = (short)0x3F80;
  const bf16x8 ones = { one_s, one_s, one_s, one_s, one_s, one_s, one_s, one_s };

  f32x4 accO[2][4] = {};
  f32x4 accL[2] = {};

  for (int t = 0; t < 32; ++t) {
    const int cb = (t & 1) ? 8192 : 0;
    u16t* const Ks = smem + cb;
    u16t* const Vs = smem + cb + 4096;
    __syncthreads();               // tile t loads complete; prev reads done
    if (t + 1 < 32) {
      const int nb = (t & 1) ? 0 : 8192;
      const int ko = (t + 1) << 6;
      GLL16(kS0 + (size_t)ko * HDD, smem + nb + dK0);
      GLL16(kS1 + (size_t)ko * HDD, smem + nb + dK1);
      GLL16(vS0 + ko, smem + nb + 4096 + dK0);
      GLL16(vS1 + ko, smem + nb + 4096 + dK1);
    }

    f32x4 sc[2][4] = {{}, {}};
    __builtin_amdgcn_s_setprio(1);           // T5: favor QK^T MFMA cluster
    #pragma unroll
    for (int ks = 0; ks < 2; ++ks) {
      const int hc = (ks << 2) + q;
      #pragma unroll
      for (int ni = 0; ni < 4; ++ni) {
        const int kr = (ni << 4) + ln;
        const bf16x8 ak = *(const bf16x8*)&Ks[((kr << 3) + (hc ^ (kr & 7))) << 3];
        #pragma unroll
        for (int g = 0; g < 2; ++g)
          sc[g][ni] = __builtin_amdgcn_mfma_f32_16x16x32_bf16(ak, qf[g][ks], sc[g][ni], 0, 0, 0);
      }
    }
    __builtin_amdgcn_s_setprio(0);

    unsigned pk01[2][4], pk23[2][4];
    #pragma unroll
    for (int g = 0; g < 2; ++g)
      #pragma unroll
      for (int ni = 0; ni < 4; ++ni) {
        const float e0 = EXP2(sc[g][ni][0]);
        const float e1 = EXP2(sc[g][ni][1]);
        const float e2 = EXP2(sc[g][ni][2]);
        const float e3 = EXP2(sc[g][ni][3]);
        pk01[g][ni] = pack_bf16_2(e0, e1);
        pk23[g][ni] = pack_bf16_2(e2, e3);
      }

    __builtin_amdgcn_s_setprio(1);           // T5: favor PV MFMA cluster
    #pragma unroll
    for (int ks = 0; ks < 2; ++ks) {
      union { unsigned u[4]; bf16x8 v; } bfv[2];
      #pragma unroll
      for (int g = 0; g < 2; ++g) {
        bfv[g].u[0] = pk01[g][(ks << 1) + 0];
        bfv[g].u[1] = pk23[g][(ks << 1) + 0];
        bfv[g].u[2] = pk01[g][(ks << 1) + 1];
        bfv[g].u[3] = pk23[g][(ks << 1) + 1];
      }
      #pragma unroll
      for (int g = 0; g < 2; ++g)
        accL[g] = __builtin_amdgcn_mfma_f32_16x16x32_bf16(ones, bfv[g].v, accL[g], 0, 0, 0);
      const int c = (ks << 2) + q;
      #pragma unroll
      for (int nio = 0; nio < 4; ++nio) {
        const int vr = (nio << 4) + ln;
        const bf16x8 av = *(const bf16x8*)&Vs[((vr << 3) + (c ^ (vr & 7))) << 3];
        #pragma unroll
        for (int g = 0; g < 2; ++g)
          accO[g][nio] = __builtin_amdgcn_mfma_f32_16x16x32_bf16(av, bfv[g].v, accO[g][nio], 0, 0, 0);
      }
    }
    __builtin_amdgcn_s_setprio(0);
  }

  // ones-MFMA makes every row of accL identical, so each lane already holds
  // the row sum l for its token (col = ln). Normalize in fp32, store once.
  __syncthreads();   // last tile's DS reads done before Os overwrite
  #pragma unroll
  for (int g = 0; g < 2; ++g) {
    const float inv = 1.0f / accL[g][0];
    const int tl = (w << 5) + (g << 4) + ln;
    #pragma unroll
    for (int nio = 0; nio < 4; ++nio) {
      uint2 pk;
      pk.x = pack_bf16_2(accO[g][nio][0] * inv, accO[g][nio][1] * inv);
      pk.y = pack_bf16_2(accO[g][nio][2] * inv, accO[g][nio][3] * inv);
      *(uint2*)&smem[tl * 72 + (nio << 4) + (q << 2)] = pk;
    }
  }
  __syncthreads();
  const int h = bh & (NHD - 1), bi = bh >> 4;
  #pragma unroll
  for (int it = 0; it < 4; ++it) {
    const int u = (it << 8) + tid;
    const int tl = u >> 3, c8 = u & 7;
    const uint4 vv = *(const uint4*)&smem[tl * 72 + (c8 << 3)];
    *(uint4*)&ctx[((size_t)(bi * SEQL + q0 + tl)) * DM + (h << 6) + (c8 << 3)] = vv;
  }
}

// ---------------------------------------------------------------------------
// Output projection: Y = X @ W^T + bias, fp32 row-major out.
// Tile 128(token) x 64(col), BK=64 (proven r4 win vs BK=32): 16 barrier
// intervals, 16 MFMA/wave/interval. LDS 48 KB; grid (16,32) = 2 blocks/CU.
// 8-chunk XOR swizzle kc^(m&7): 2-way LDS conflict (free), GLL-linear dest.
// ---------------------------------------------------------------------------
__global__ __launch_bounds__(256) void outproj_kernel(
    const u16t* __restrict__ A, const u16t* __restrict__ W,
    const float* __restrict__ bias, float* __restrict__ outF)
{
  __shared__ alignas(16) u16t smem[24576];  // A0@0 B0@8192 A1@12288 B1@20480

  const int tid = threadIdx.x;
  const int l = tid & 63, w = tid >> 6, q = l >> 4, ln = l & 15;
  const int row0 = blockIdx.y << 7;   // token base
  const int col0 = blockIdx.x << 6;   // col base
  const int wm = (w >> 1) << 6, wn = (w & 1) << 5;

  // BK=64 staging: A 1024 units (4/thread), B 512 units (2/thread); unit=8 elems
  const u16t* gA[4]; const u16t* gB[2];
  int dA[4], dB[2];
  #pragma unroll
  for (int p = 0; p < 4; ++p) {
    const int s = tid + (p << 8);
    const int m = s >> 3, kc = (s & 7) ^ (m & 7);
    gA[p] = A + (size_t)(row0 + m) * DM + (kc << 3);
    dA[p] = s << 3;
  }
  #pragma unroll
  for (int p = 0; p < 2; ++p) {
    const int s = tid + (p << 8);
    const int m = s >> 3, kc = (s & 7) ^ (m & 7);
    gB[p] = W + (size_t)(col0 + m) * DM + (kc << 3);
    dB[p] = s << 3;
  }

  f32x4 acc[4][2] = {};

  #pragma unroll
  for (int p = 0; p < 4; ++p) GLL16(gA[p], smem + dA[p]);
  #pragma unroll
  for (int p = 0; p < 2; ++p) GLL16(gB[p], smem + 8192 + dB[p]);

  for (int t = 0; t < 16; ++t) {
    u16t* const curA = smem + ((t & 1) ? 12288 : 0);
    u16t* const curB = smem + ((t & 1) ? 20480 : 8192);
    __syncthreads();                 // tile t loads complete; prev reads done
    if (t + 1 < 16) {
      u16t* const nA = smem + ((t & 1) ? 0 : 12288);
      u16t* const nB = smem + ((t & 1) ? 8192 : 20480);
      const int kt = (t + 1) << 6;
      #pragma unroll
      for (int p = 0; p < 4; ++p) GLL16(gA[p] + kt, nA + dA[p]);
      #pragma unroll
      for (int p = 0; p < 2; ++p) GLL16(gB[p] + kt, nB + dB[p]);
    }

    #pragma unroll
    for (int ks = 0; ks < 2; ++ks) {
      const int hc = (ks << 2) + q;
      bf16x8 af[4], bfr[2];
      #pragma unroll
      for (int mi = 0; mi < 4; ++mi) {
        const int r = wm + (mi << 4) + ln;
        af[mi] = *(const bf16x8*)&curA[((r << 3) + (hc ^ (r & 7))) << 3];
      }
      #pragma unroll
      for (int ni = 0; ni < 2; ++ni) {
        const int r = wn + (ni << 4) + ln;
        bfr[ni] = *(const bf16x8*)&curB[((r << 3) + (hc ^ (r & 7))) << 3];
      }
      #pragma unroll
      for (int mi = 0; mi < 4; ++mi)
        #pragma unroll
        for (int ni = 0; ni < 2; ++ni)
          acc[mi][ni] = __builtin_amdgcn_mfma_f32_16x16x32_bf16(af[mi], bfr[ni], acc[mi][ni], 0, 0, 0);
    }
  }

  #pragma unroll
  for (int ni = 0; ni < 2; ++ni) {
    const int col = col0 + wn + (ni << 4) + ln;
    const float bv = bias[col];
    #pragma unroll
    for (int mi = 0; mi < 4; ++mi)
      #pragma unroll
      for (int r = 0; r < 4; ++r) {
        const int row = row0 + wm + (mi << 4) + (q << 2) + r;
        outF[(size_t)row * DM + col] = acc[mi][ni][r] + bv;
      }
  }
}

// ---------------------------------------------------------------------------
extern "C" void kernel_launch(void* const* d_in, const int* in_sizes, int n_in,
                              void* d_out, int out_size, void* d_ws, size_t ws_size,
                              hipStream_t stream)
{
  const float* x  = (const float*)d_in[0];
  const float* Wq = (const float*)d_in[1];
  const float* bq = (const float*)d_in[2];
  const float* Wk = (const float*)d_in[3];
  const float* bk = (const float*)d_in[4];
  const float* Wv = (const float*)d_in[5];
  const float* bv = (const float*)d_in[6];
  const float* Wo = (const float*)d_in[7];
  const float* bo = (const float*)d_in[8];
  float* out = (float*)d_out;

  // Write-once workspace plan (no aliasing, no in-place updates):
  u16t* p = (u16t*)d_ws;
  u16t* xb  = p;  p += 4194304;   // x bf16
  u16t* Wqb = p;  p += 1048576;
  u16t* Wkb = p;  p += 1048576;
  u16t* Wvb = p;  p += 1048576;
  u16t* Wob = p;  p += 1048576;
  u16t* Qbf = p;  p += 4194304;
  u16t* Kbf = p;  p += 4194304;
  u16t* Vtb = p;  p += 4194304;
  u16t* ctx = p;  p += 4194304;   // normalized attention output, bf16

  ConvArgs ca;
  ca.src[0] = x;  ca.dst[0] = xb;
  ca.src[1] = Wq; ca.dst[1] = Wqb;
  ca.src[2] = Wk; ca.dst[2] = Wkb;
  ca.src[3] = Wv; ca.dst[3] = Wvb;
  ca.src[4] = Wo; ca.dst[4] = Wob;
  conv_kernel<<<8192, 256, 0, stream>>>(ca);

  QKVArgs qa;
  qa.W[0] = Wqb; qa.W[1] = Wkb; qa.W[2] = Wvb;
  qa.b[0] = bq;  qa.b[1] = bk;  qa.b[2] = bv;
  qa.dst[0] = Qbf; qa.dst[1] = Kbf; qa.dst[2] = Vtb;
  // z=0: fused Q+K (X staged once); z=1: V.  512 blocks -> 1 QK + 1 V per CU.
  qkv_kernel<<<dim3(8, 32, 2), 256, 0, stream>>>(xb, qa);

  // bh on x: linear block id === bh (mod 8) -> per-head K/V pinned to one XCD L2
  attn_kernel<<<dim3(32, 16), 256, 0, stream>>>(Qbf, Kbf, Vtb, ctx);

  outproj_kernel<<<dim3(16, 32), 256, 0, stream>>>(ctx, Wob, bo, out);
}

// Round 11
// 171.660 us; speedup vs baseline: 1.0822x; 1.0822x over previous
//
#include <hip/hip_runtime.h>

typedef unsigned short u16t;
typedef __attribute__((ext_vector_type(8))) short bf16x8;
typedef __attribute__((ext_vector_type(4))) float f32x4;

#define DM   1024
#define SEQL 2048
#define NHD  16
#define HDD  64

#define GLL16(g, l) __builtin_amdgcn_global_load_lds( \
    (const __attribute__((address_space(1))) void*)(g), \
    (__attribute__((address_space(3))) void*)(l), 16, 0, 0)

#if defined(__has_builtin)
#if __has_builtin(__builtin_amdgcn_exp2f)
#define EXP2(x) __builtin_amdgcn_exp2f(x)
#else
#define EXP2(x) exp2f(x)
#endif
#else
#define EXP2(x) exp2f(x)
#endif

__device__ __forceinline__ u16t f2bf(float f) {
  unsigned u = __float_as_uint(f);
  return (u16t)((u + 0x7fffu + ((u >> 16) & 1u)) >> 16);   // RNE
}
// pack two finite floats to (bf16(a) | bf16(b)<<16), round-half-up
// (PROVEN numerics: 7.3e-4 absmax; v_cvt_pk_bf16_f32 regressed to 9e-3 — its
// rounding does not match, do not substitute)
__device__ __forceinline__ unsigned pack_bf16_2(float a, float b) {
  const unsigned ua = __float_as_uint(a) + 0x8000u;
  const unsigned ub = __float_as_uint(b) + 0x8000u;
  return __builtin_amdgcn_perm(ub, ua, 0x07060302);
}

// ---------------------------------------------------------------------------
// fp32 -> bf16 conversion: x (4M elems) + 4 weights (1M each)
// ---------------------------------------------------------------------------
struct ConvArgs { const float* src[5]; u16t* dst[5]; };

__global__ __launch_bounds__(256) void conv_kernel(ConvArgs a) {
  const int gid = blockIdx.x * 256 + threadIdx.x;
  const int e = gid << 2;
  int sel, off;
  if (e < 4194304) { sel = 0; off = e; }
  else { const int r = e - 4194304; sel = 1 + (r >> 20); off = r & 1048575; }
  const float4 f = *(const float4*)(a.src[sel] + off);
  union { u16t s[4]; uint2 u; } o;
  o.s[0] = f2bf(f.x); o.s[1] = f2bf(f.y); o.s[2] = f2bf(f.z); o.s[3] = f2bf(f.w);
  *(uint2*)(a.dst[sel] + off) = o.u;
}

__device__ __forceinline__ int gslot(int m, int kc) { return (m << 2) + (kc ^ ((m >> 1) & 3)); }

// ---------------------------------------------------------------------------
// QKV GEMM.  X:[4096][1024], W:[1024][1024] rm.  128(token)x128(d) tile, BK=32.
// PROVEN r4/r9 form. Experiments ruled out: 128x64/BK=64 (+50% staged bytes,
// r5); fused Q+K (VGPR 160, QK/V block imbalance -> occ 10%, MfmaUtil 20%,
// qkv 50us, r10). The 3-way z split's equal blocks at 3/CU is the optimum.
// Double-buffered GLL pipeline; epilogue Es aliases staging (barrier-guarded).
// MODE 1 (Q,K): computes Y^T (operand swap) -> coalesced 16B stores [bh][n][hd]
// MODE 2 (V): normal orientation, token groups permuted by pos(), stored as
//   V^T [bh][hd][n'] so the attention PV A-fragment is one ds_read_b128.
// ---------------------------------------------------------------------------
template<int MODE>
__device__ __forceinline__ void qkv_body(
    const u16t* __restrict__ X, const u16t* __restrict__ W,
    const float* __restrict__ bias, float oscale, u16t* __restrict__ outB,
    u16t* smem)
{
  u16t* const Es = smem;                 // 17408 elems, aliases staging

  const int tid = threadIdx.x;
  const int l = tid & 63, w = tid >> 6, q = l >> 4, ln = l & 15;
  const int trow0 = blockIdx.y << 7;    // token tile base
  const int dcol0 = blockIdx.x << 7;    // d tile base
  const int wm = (w >> 1) << 6, wn = (w & 1) << 6;

  const int s0 = (w << 6) + l, s1 = s0 + 256;
  const int m0 = s0 >> 2, kc0 = (s0 & 3) ^ ((m0 >> 1) & 3);
  const int m1 = s1 >> 2, kc1 = (s1 & 3) ^ ((m1 >> 1) & 3);
  const u16t* gA0 = X + (size_t)(trow0 + m0) * DM + (kc0 << 3);
  const u16t* gA1 = X + (size_t)(trow0 + m1) * DM + (kc1 << 3);
  const u16t* gB0 = W + (size_t)(dcol0 + m0) * DM + (kc0 << 3);
  const u16t* gB1 = W + (size_t)(dcol0 + m1) * DM + (kc1 << 3);
  const int dO0 = (w << 6) << 3;               // LDS elem offsets
  const int dO1 = ((w << 6) + 256) << 3;

  f32x4 acc[4][4] = {};

  GLL16(gA0, smem + dO0);
  GLL16(gA1, smem + dO1);
  GLL16(gB0, smem + 4096 + dO0);
  GLL16(gB1, smem + 4096 + dO1);

  for (int kt = 0; kt < DM; kt += 32) {
    const int it = kt >> 5;
    u16t* const curA = smem + ((it & 1) ? 8192 : 0);
    u16t* const curB = curA + 4096;
    __syncthreads();                   // tile `it` loads complete; prev reads done
    if (kt + 32 < DM) {                // prefetch tile it+1 into alt buffer
      u16t* const nA = smem + ((it & 1) ? 0 : 8192);
      u16t* const nB = nA + 4096;
      GLL16(gA0 + kt + 32, nA + dO0);
      GLL16(gA1 + kt + 32, nA + dO1);
      GLL16(gB0 + kt + 32, nB + dO0);
      GLL16(gB1 + kt + 32, nB + dO1);
    }

    bf16x8 af[4], bfr[4];
    #pragma unroll
    for (int mi = 0; mi < 4; ++mi) {
      const int r = wm + (mi << 4) + ln;
      af[mi] = *(const bf16x8*)&((MODE == 1 ? curB : curA)[gslot(r, q) << 3]);
    }
    #pragma unroll
    for (int ni = 0; ni < 4; ++ni) {
      const int r = wn + (ni << 4) + ln;
      bfr[ni] = *(const bf16x8*)&((MODE == 1 ? curA : curB)[gslot(r, q) << 3]);
    }
    #pragma unroll
    for (int mi = 0; mi < 4; ++mi)
      #pragma unroll
      for (int ni = 0; ni < 4; ++ni)
        acc[mi][ni] = __builtin_amdgcn_mfma_f32_16x16x32_bf16(af[mi], bfr[ni], acc[mi][ni], 0, 0, 0);
  }

  __syncthreads();   // staging dead; Es (aliased) now safe to write

  if (MODE == 1) {
    #pragma unroll
    for (int mi = 0; mi < 4; ++mi) {
      const int dl = wm + (mi << 4) + (q << 2);
      const float4 b4 = *(const float4*)&bias[dcol0 + dl];
      #pragma unroll
      for (int ni = 0; ni < 4; ++ni) {
        const int tl = wn + (ni << 4) + ln;
        uint2 pk;
        pk.x = pack_bf16_2((acc[mi][ni][0] + b4.x) * oscale, (acc[mi][ni][1] + b4.y) * oscale);
        pk.y = pack_bf16_2((acc[mi][ni][2] + b4.z) * oscale, (acc[mi][ni][3] + b4.w) * oscale);
        *(uint2*)&Es[tl * 136 + dl] = pk;
      }
    }
    __syncthreads();
    #pragma unroll
    for (int it = 0; it < 8; ++it) {
      const int u = (it << 8) + tid;
      const int tl = u >> 4, c8 = u & 15;
      const uint4 vv = *(const uint4*)&Es[tl * 136 + (c8 << 3)];
      const int tok = trow0 + tl;
      const int b = tok >> 11, n = tok & (SEQL - 1);
      const int dg = dcol0 + (c8 << 3);
      const int h = dg >> 6, hd = dg & 63;
      *(uint4*)&outB[((size_t)(b * NHD + h) * SEQL + n) * HDD + hd] = vv;
    }
  } else {
    #pragma unroll
    for (int ni = 0; ni < 4; ++ni) {
      const int dl = wn + (ni << 4) + ln;
      const float bv = bias[dcol0 + dl];
      #pragma unroll
      for (int mi = 0; mi < 4; ++mi) {
        const int g = (wm >> 2) + (mi << 2) + q;   // token group (of 4), 0..31
        const int g6 = g & 15;
        const int gp = (g & 16) | (g6 & 8) | ((g6 & 3) << 1) | ((g6 >> 2) & 1);
        uint2 pk;
        pk.x = pack_bf16_2(acc[mi][ni][0] + bv, acc[mi][ni][1] + bv);
        pk.y = pack_bf16_2(acc[mi][ni][2] + bv, acc[mi][ni][3] + bv);
        *(uint2*)&Es[dl * 136 + (gp << 2)] = pk;
      }
    }
    __syncthreads();
    #pragma unroll
    for (int it = 0; it < 8; ++it) {
      const int u = (it << 8) + tid;
      const int dl = u >> 4, c8 = u & 15;
      const uint4 vv = *(const uint4*)&Es[dl * 136 + (c8 << 3)];
      const int dg = dcol0 + dl;
      const int h = dg >> 6, hd = dg & 63;
      const int b = trow0 >> 11;
      const int n = (trow0 & (SEQL - 1)) + (c8 << 3);
      *(uint4*)&outB[((size_t)(b * NHD + h) * HDD + hd) * SEQL + n] = vv;
    }
  }
}

struct QKVArgs { const u16t* W[3]; const float* b[3]; u16t* dst[3]; };

__global__ __launch_bounds__(256) void qkv_kernel(const u16t* __restrict__ X, QKVArgs g) {
  __shared__ alignas(16) u16t smem[17408];
  const int z = blockIdx.z;
  if (z == 2)      qkv_body<2>(X, g.W[2], g.b[2], 1.0f, g.dst[2], smem);
  else if (z == 1) qkv_body<1>(X, g.W[1], g.b[1], 1.0f, g.dst[1], smem);
  else             qkv_body<1>(X, g.W[0], g.b[0], 0.04508422f, g.dst[0], smem);
  // Q pre-scaled by log2(e)/32 so attention uses exp2 directly
}

// ---------------------------------------------------------------------------
// MFMA flash attention, SINGLE PASS over all 2048 keys. Q-TILE=128, KVBLK=64,
// double-buffered __syncthreads staging — the PROVEN r7/r9 configuration
// (~43-46us, VGPR 64, 98K conflicts). Axes exhausted: q-64 (+staging),
// KV-128 (22x conflicts), depth-2 vmcnt+sched_barrier (m141 failure mode).
// T5 setprio around MFMA clusters kept (r7: 46.1->43.3us, m191 regime).
// Block = (bh on x, q-tile on y) -> 512 blocks; linear id === bh (mod 8)
// pins each head's K/V to one XCD L2. Q direct global->regs. Row sums via
// ones-MFMA; P = exp2(S') since Q carries log2e/32. O normalized in-register.
// ---------------------------------------------------------------------------
__global__ __launch_bounds__(256, 4) void attn_kernel(
    const u16t* __restrict__ Qb, const u16t* __restrict__ Kb,
    const u16t* __restrict__ Vt, u16t* __restrict__ ctx)
{
  __shared__ alignas(16) u16t smem[16384];   // 32 KB: K/V dbuf; Os aliases

  const int tid = threadIdx.x;              // 0..255
  const int l = tid & 63, w = tid >> 6;     // wave 0..3
  const int q = l >> 4, ln = l & 15;
  const int bh = blockIdx.x, q0 = blockIdx.y << 7;
  const size_t hb = (size_t)bh * SEQL * HDD;
  const u16t* Qg = Qb + hb;
  const u16t* Kg = Kb + hb;
  const u16t* Vg = Vt + hb;   // [hd][n-permuted]

  bf16x8 qf[2][2];
  #pragma unroll
  for (int g = 0; g < 2; ++g) {
    const int qr = q0 + (w << 5) + (g << 4) + ln;
    #pragma unroll
    for (int ks = 0; ks < 2; ++ks)
      qf[g][ks] = *(const bf16x8*)(Qg + (size_t)qr * HDD + (((ks << 2) + q) << 3));
  }

  const int u0 = tid,       r0 = u0 >> 3, c0 = (u0 & 7) ^ (r0 & 7);
  const int u1 = 256 + tid, r1 = u1 >> 3, c1 = (u1 & 7) ^ (r1 & 7);
  const u16t* const kS0 = Kg + (size_t)r0 * HDD + (c0 << 3);
  const u16t* const kS1 = Kg + (size_t)r1 * HDD + (c1 << 3);
  const u16t* const vS0 = Vg + (size_t)r0 * SEQL + (c0 << 3);
  const u16t* const vS1 = Vg + (size_t)r1 * SEQL + (c1 << 3);
  const int dK0 = (w << 6) << 3, dK1 = (256 + (w << 6)) << 3;

  GLL16(kS0, smem + dK0);
  GLL16(kS1, smem + dK1);
  GLL16(vS0, smem + 4096 + dK0);
  GLL16(vS1, smem + 4096 + dK1);

  const short one_s = (short)0x3F80;
  const bf16x8 ones = { one_s, one_s, one_s, one_s, one_s, one_s, one_s, one_s };

  f32x4 accO[2][4] = {};
  f32x4 accL[2] = {};

  for (int t = 0; t < 32; ++t) {
    const int cb = (t & 1) ? 8192 : 0;
    u16t* const Ks = smem + cb;
    u16t* const Vs = smem + cb + 4096;
    __syncthreads();               // tile t loads complete; prev reads done
    if (t + 1 < 32) {
      const int nb = (t & 1) ? 0 : 8192;
      const int ko = (t + 1) << 6;
      GLL16(kS0 + (size_t)ko * HDD, smem + nb + dK0);
      GLL16(kS1 + (size_t)ko * HDD, smem + nb + dK1);
      GLL16(vS0 + ko, smem + nb + 4096 + dK0);
      GLL16(vS1 + ko, smem + nb + 4096 + dK1);
    }

    f32x4 sc[2][4] = {{}, {}};
    __builtin_amdgcn_s_setprio(1);           // T5: favor QK^T MFMA cluster
    #pragma unroll
    for (int ks = 0; ks < 2; ++ks) {
      const int hc = (ks << 2) + q;
      #pragma unroll
      for (int ni = 0; ni < 4; ++ni) {
        const int kr = (ni << 4) + ln;
        const bf16x8 ak = *(const bf16x8*)&Ks[((kr << 3) + (hc ^ (kr & 7))) << 3];
        #pragma unroll
        for (int g = 0; g < 2; ++g)
          sc[g][ni] = __builtin_amdgcn_mfma_f32_16x16x32_bf16(ak, qf[g][ks], sc[g][ni], 0, 0, 0);
      }
    }
    __builtin_amdgcn_s_setprio(0);

    unsigned pk01[2][4], pk23[2][4];
    #pragma unroll
    for (int g = 0; g < 2; ++g)
      #pragma unroll
      for (int ni = 0; ni < 4; ++ni) {
        const float e0 = EXP2(sc[g][ni][0]);
        const float e1 = EXP2(sc[g][ni][1]);
        const float e2 = EXP2(sc[g][ni][2]);
        const float e3 = EXP2(sc[g][ni][3]);
        pk01[g][ni] = pack_bf16_2(e0, e1);
        pk23[g][ni] = pack_bf16_2(e2, e3);
      }

    __builtin_amdgcn_s_setprio(1);           // T5: favor PV MFMA cluster
    #pragma unroll
    for (int ks = 0; ks < 2; ++ks) {
      union { unsigned u[4]; bf16x8 v; } bfv[2];
      #pragma unroll
      for (int g = 0; g < 2; ++g) {
        bfv[g].u[0] = pk01[g][(ks << 1) + 0];
        bfv[g].u[1] = pk23[g][(ks << 1) + 0];
        bfv[g].u[2] = pk01[g][(ks << 1) + 1];
        bfv[g].u[3] = pk23[g][(ks << 1) + 1];
      }
      #pragma unroll
      for (int g = 0; g < 2; ++g)
        accL[g] = __builtin_amdgcn_mfma_f32_16x16x32_bf16(ones, bfv[g].v, accL[g], 0, 0, 0);
      const int c = (ks << 2) + q;
      #pragma unroll
      for (int nio = 0; nio < 4; ++nio) {
        const int vr = (nio << 4) + ln;
        const bf16x8 av = *(const bf16x8*)&Vs[((vr << 3) + (c ^ (vr & 7))) << 3];
        #pragma unroll
        for (int g = 0; g < 2; ++g)
          accO[g][nio] = __builtin_amdgcn_mfma_f32_16x16x32_bf16(av, bfv[g].v, accO[g][nio], 0, 0, 0);
      }
    }
    __builtin_amdgcn_s_setprio(0);
  }

  // ones-MFMA makes every row of accL identical, so each lane already holds
  // the row sum l for its token (col = ln). Normalize in fp32, store once.
  __syncthreads();   // last tile's DS reads done before Os overwrite
  #pragma unroll
  for (int g = 0; g < 2; ++g) {
    const float inv = 1.0f / accL[g][0];
    const int tl = (w << 5) + (g << 4) + ln;
    #pragma unroll
    for (int nio = 0; nio < 4; ++nio) {
      uint2 pk;
      pk.x = pack_bf16_2(accO[g][nio][0] * inv, accO[g][nio][1] * inv);
      pk.y = pack_bf16_2(accO[g][nio][2] * inv, accO[g][nio][3] * inv);
      *(uint2*)&smem[tl * 72 + (nio << 4) + (q << 2)] = pk;
    }
  }
  __syncthreads();
  const int h = bh & (NHD - 1), bi = bh >> 4;
  #pragma unroll
  for (int it = 0; it < 4; ++it) {
    const int u = (it << 8) + tid;
    const int tl = u >> 3, c8 = u & 7;
    const uint4 vv = *(const uint4*)&smem[tl * 72 + (c8 << 3)];
    *(uint4*)&ctx[((size_t)(bi * SEQL + q0 + tl)) * DM + (h << 6) + (c8 << 3)] = vv;
  }
}

// ---------------------------------------------------------------------------
// Output projection: Y = X @ W^T + bias, fp32 row-major out.
// Tile 128(token) x 64(col), BK=64 (proven r4 win vs BK=32): 16 barrier
// intervals, 16 MFMA/wave/interval. LDS 48 KB; grid (16,32) = 2 blocks/CU.
// 8-chunk XOR swizzle kc^(m&7): 2-way LDS conflict (free), GLL-linear dest.
// ---------------------------------------------------------------------------
__global__ __launch_bounds__(256) void outproj_kernel(
    const u16t* __restrict__ A, const u16t* __restrict__ W,
    const float* __restrict__ bias, float* __restrict__ outF)
{
  __shared__ alignas(16) u16t smem[24576];  // A0@0 B0@8192 A1@12288 B1@20480

  const int tid = threadIdx.x;
  const int l = tid & 63, w = tid >> 6, q = l >> 4, ln = l & 15;
  const int row0 = blockIdx.y << 7;   // token base
  const int col0 = blockIdx.x << 6;   // col base
  const int wm = (w >> 1) << 6, wn = (w & 1) << 5;

  // BK=64 staging: A 1024 units (4/thread), B 512 units (2/thread); unit=8 elems
  const u16t* gA[4]; const u16t* gB[2];
  int dA[4], dB[2];
  #pragma unroll
  for (int p = 0; p < 4; ++p) {
    const int s = tid + (p << 8);
    const int m = s >> 3, kc = (s & 7) ^ (m & 7);
    gA[p] = A + (size_t)(row0 + m) * DM + (kc << 3);
    dA[p] = s << 3;
  }
  #pragma unroll
  for (int p = 0; p < 2; ++p) {
    const int s = tid + (p << 8);
    const int m = s >> 3, kc = (s & 7) ^ (m & 7);
    gB[p] = W + (size_t)(col0 + m) * DM + (kc << 3);
    dB[p] = s << 3;
  }

  f32x4 acc[4][2] = {};

  #pragma unroll
  for (int p = 0; p < 4; ++p) GLL16(gA[p], smem + dA[p]);
  #pragma unroll
  for (int p = 0; p < 2; ++p) GLL16(gB[p], smem + 8192 + dB[p]);

  for (int t = 0; t < 16; ++t) {
    u16t* const curA = smem + ((t & 1) ? 12288 : 0);
    u16t* const curB = smem + ((t & 1) ? 20480 : 8192);
    __syncthreads();                 // tile t loads complete; prev reads done
    if (t + 1 < 16) {
      u16t* const nA = smem + ((t & 1) ? 0 : 12288);
      u16t* const nB = smem + ((t & 1) ? 8192 : 20480);
      const int kt = (t + 1) << 6;
      #pragma unroll
      for (int p = 0; p < 4; ++p) GLL16(gA[p] + kt, nA + dA[p]);
      #pragma unroll
      for (int p = 0; p < 2; ++p) GLL16(gB[p] + kt, nB + dB[p]);
    }

    #pragma unroll
    for (int ks = 0; ks < 2; ++ks) {
      const int hc = (ks << 2) + q;
      bf16x8 af[4], bfr[2];
      #pragma unroll
      for (int mi = 0; mi < 4; ++mi) {
        const int r = wm + (mi << 4) + ln;
        af[mi] = *(const bf16x8*)&curA[((r << 3) + (hc ^ (r & 7))) << 3];
      }
      #pragma unroll
      for (int ni = 0; ni < 2; ++ni) {
        const int r = wn + (ni << 4) + ln;
        bfr[ni] = *(const bf16x8*)&curB[((r << 3) + (hc ^ (r & 7))) << 3];
      }
      #pragma unroll
      for (int mi = 0; mi < 4; ++mi)
        #pragma unroll
        for (int ni = 0; ni < 2; ++ni)
          acc[mi][ni] = __builtin_amdgcn_mfma_f32_16x16x32_bf16(af[mi], bfr[ni], acc[mi][ni], 0, 0, 0);
    }
  }

  #pragma unroll
  for (int ni = 0; ni < 2; ++ni) {
    const int col = col0 + wn + (ni << 4) + ln;
    const float bv = bias[col];
    #pragma unroll
    for (int mi = 0; mi < 4; ++mi)
      #pragma unroll
      for (int r = 0; r < 4; ++r) {
        const int row = row0 + wm + (mi << 4) + (q << 2) + r;
        outF[(size_t)row * DM + col] = acc[mi][ni][r] + bv;
      }
  }
}

// ---------------------------------------------------------------------------
extern "C" void kernel_launch(void* const* d_in, const int* in_sizes, int n_in,
                              void* d_out, int out_size, void* d_ws, size_t ws_size,
                              hipStream_t stream)
{
  const float* x  = (const float*)d_in[0];
  const float* Wq = (const float*)d_in[1];
  const float* bq = (const float*)d_in[2];
  const float* Wk = (const float*)d_in[3];
  const float* bk = (const float*)d_in[4];
  const float* Wv = (const float*)d_in[5];
  const float* bv = (const float*)d_in[6];
  const float* Wo = (const float*)d_in[7];
  const float* bo = (const float*)d_in[8];
  float* out = (float*)d_out;

  // Write-once workspace plan (no aliasing, no in-place updates):
  u16t* p = (u16t*)d_ws;
  u16t* xb  = p;  p += 4194304;   // x bf16
  u16t* Wqb = p;  p += 1048576;
  u16t* Wkb = p;  p += 1048576;
  u16t* Wvb = p;  p += 1048576;
  u16t* Wob = p;  p += 1048576;
  u16t* Qbf = p;  p += 4194304;
  u16t* Kbf = p;  p += 4194304;
  u16t* Vtb = p;  p += 4194304;
  u16t* ctx = p;  p += 4194304;   // normalized attention output, bf16

  ConvArgs ca;
  ca.src[0] = x;  ca.dst[0] = xb;
  ca.src[1] = Wq; ca.dst[1] = Wqb;
  ca.src[2] = Wk; ca.dst[2] = Wkb;
  ca.src[3] = Wv; ca.dst[3] = Wvb;
  ca.src[4] = Wo; ca.dst[4] = Wob;
  conv_kernel<<<8192, 256, 0, stream>>>(ca);

  QKVArgs qa;
  qa.W[0] = Wqb; qa.W[1] = Wkb; qa.W[2] = Wvb;
  qa.b[0] = bq;  qa.b[1] = bk;  qa.b[2] = bv;
  qa.dst[0] = Qbf; qa.dst[1] = Kbf; qa.dst[2] = Vtb;
  qkv_kernel<<<dim3(8, 32, 3), 256, 0, stream>>>(xb, qa);

  // bh on x: linear block id === bh (mod 8) -> per-head K/V pinned to one XCD L2
  attn_kernel<<<dim3(32, 16), 256, 0, stream>>>(Qbf, Kbf, Vtb, ctx);

  outproj_kernel<<<dim3(16, 32), 256, 0, stream>>>(ctx, Wob, bo, out);
}